// Round 13
// baseline (200.659 us; speedup 1.0000x reference)
//
#include <hip/hip_runtime.h>

// GCN 2-layer, R26 = R25 with gathers switched to QUARTER-WAVE x ushort8
// (16 B/lane, the coalescing sweet spot): each wave-instr moves 1KB (4 rows)
// vs 512B, halving load-instr count per edge and doubling in-flight bytes.
// Little's-law at R25: 21 waves x 8 x 512B = 86KB/CU in flight -> 6.8 B/cy
// observed; this raises window to ~256KB/CU. gemm_fused tile widens to 32
// rows (512 thr, 8 waves, 32 quarter-waves), LDS 25.6KB -> 4 blk/CU = 32
// waves. Depth stays 8 (R24: 16 thrashed). Rank-sort retained (R21 tripwire).
//   wswz(+ctrl zero) | bin | bucket_csr(rank-sort,dinv,Xs) | gemm_fused | gather2
// Lessons: R7 R9 R11 R14 R16 R17 R18 R19 R21 R22 R23 R24 (see git log);
// depth>8 thrashes; venue+parallelism for canonicalization; spills kill.

typedef short bf16x8 __attribute__((ext_vector_type(8)));
typedef unsigned short u16x8 __attribute__((ext_vector_type(8)));
typedef float f32x4 __attribute__((ext_vector_type(4)));

#define LDSTRIDE 264   // H tile row stride (ushort)
#define XTSTRIDE 136   // A tile row stride (ushort)
#define BSHIFT 7       // 128 dsts per bucket
#define BMASK 127
#define CAPMAX 3072    // sh_col capacity (ints); host cap must be <= this

__device__ inline unsigned short f2bf(float f) {          // RNE
    unsigned int u = __float_as_uint(f);
    u += 0x7FFF + ((u >> 16) & 1);
    return (unsigned short)(u >> 16);
}
__device__ inline float bf2f(unsigned short h) {
    return __uint_as_float(((unsigned int)h) << 16);
}

// ---------- W swizzle into MFMA b-frag order + ctrl zero ----------
__device__ inline void swz1(const float* W, unsigned short* Ws, int K, int N, int i) {
    int k = i / N, n = i % N;
    int KC = K >> 5;
    size_t d = ((((size_t)(n >> 4) * KC + (k >> 5)) * 64) + ((k >> 3) & 3) * 16 + (n & 15)) * 8
               + (k & 7);
    Ws[d] = f2bf(W[i]);
}
__global__ void wswz_kernel(const float* __restrict__ W1, const float* __restrict__ W2,
                            unsigned short* __restrict__ W1s, unsigned short* __restrict__ W2s,
                            int* __restrict__ ctrl) {
    int i = blockIdx.x * blockDim.x + threadIdx.x;
    if (blockIdx.x == 0) {                     // zero ALL 512 ctrl ints
        for (int j = threadIdx.x; j < 512; j += 256) ctrl[j] = 0;
    }
    if (i < 32768) swz1(W1, W1s, 128, 256, i);
    else if (i < 65536) swz1(W2, W2s, 256, 128, i - 32768);
}

// ---------- pass 1: bin edges by dst>>7 (4 B packed) ----------
__global__ __launch_bounds__(256) void bin_kernel(
    const int* __restrict__ src, const int* __restrict__ dst,
    int* __restrict__ bcur, unsigned int* __restrict__ bbuf,
    int E, int cap, int nbuck) {
    __shared__ int cnt[512];
    __shared__ int base[512];
    int t = threadIdx.x;
    for (int i = t; i < nbuck; i += 256) cnt[i] = 0;
    __syncthreads();
    int e0 = blockIdx.x * 2048;
    unsigned int p_[8];
    int b_[8];
#pragma unroll
    for (int i = 0; i < 8; i++) {
        int e = e0 + i * 256 + t;
        if (e < E) {
            int s = src[e], d = dst[e];
            b_[i] = d >> BSHIFT;
            p_[i] = ((unsigned)(d & BMASK) << 24) | (unsigned)s;   // N < 2^24
            atomicAdd(&cnt[b_[i]], 1);
        } else b_[i] = -1;
    }
    __syncthreads();
    for (int b = t; b < nbuck; b += 256) {
        int c = cnt[b];
        base[b] = (c > 0) ? atomicAdd(&bcur[b], c) : 0;
    }
    __syncthreads();
    for (int i = t; i < nbuck; i += 256) cnt[i] = 0;   // reuse as cursor
    __syncthreads();
#pragma unroll
    for (int i = 0; i < 8; i++) {
        if (b_[i] >= 0) {
            int b = b_[i];
            int p = base[b] + atomicAdd(&cnt[b], 1);
            if (p >= 0 && p < cap) bbuf[(size_t)b * cap + p] = p_[i];
        }
    }
}

// ---------- pass 2: per-bucket (128 dsts) CSR + parallel rank sort + Xs ----------
__global__ __launch_bounds__(256) void bucket_csr_kernel(
    const int* __restrict__ bcur, const unsigned int* __restrict__ bbuf,
    const float* __restrict__ x,
    int* __restrict__ col, int* __restrict__ rowbeg, int* __restrict__ rowend,
    float* __restrict__ dinv, unsigned short* __restrict__ Xs, int N, int cap) {
    __shared__ int ldeg[128];
    __shared__ int sbeg[128];
    __shared__ int lrp[256];
    __shared__ float sdv[128];
    __shared__ int sh_col[CAPMAX];               // 12288 B: packed (row<<24)|src
    int b = blockIdx.x, t = threadIdx.x;
    int cnt = min(max(bcur[b], 0), cap);
    if (t < 128) ldeg[t] = 0;
    __syncthreads();
    const unsigned int* mybuf = bbuf + (size_t)b * cap;
    for (int i = t; i < cnt; i += 256)
        atomicAdd(&ldeg[mybuf[i] >> 24], 1);
    __syncthreads();
    int v = (t < 128) ? ldeg[t] : 0;
    lrp[t] = v;
    __syncthreads();
    for (int off = 1; off < 128; off <<= 1) {    // inclusive scan (128 live)
        int u = (t >= off) ? lrp[t - off] : 0;
        __syncthreads();
        lrp[t] += u;
        __syncthreads();
    }
    int excl = lrp[t] - v;
    int gbase = b * cap;
    if (t < 128) {
        int r = b * 128 + t;
        float dv = rsqrtf((float)v + 1.0f);      // self-loop adds 1
        sdv[t] = dv;
        if (r < N) {
            rowbeg[r] = gbase + excl;
            rowend[r] = gbase + excl + v;
            dinv[r] = dv;
        }
        sbeg[t] = excl;    // segment start (stable)
        ldeg[t] = excl;    // LOCAL scatter cursor
    }
    __syncthreads();
    for (int i = t; i < cnt; i += 256) {         // scatter packed vals into LDS
        unsigned int pr = mybuf[i];
        int p = atomicAdd(&ldeg[pr >> 24], 1);
        sh_col[p] = (int)pr;                     // keep row bits for compare
    }
    __syncthreads();
    // deterministic order via PARALLEL rank sort (R23/R24 lessons): slot =
    // seg_start + #{v_j < v_i} + #{v_j == v_i && j < i}; ties interchangeable
    // -> array content launch-invariant; independent LDS reads, no chains.
    for (int i = t; i < cnt; i += 256) {
        int vi = sh_col[i];
        int row = ((unsigned)vi) >> 24;
        int s0 = sbeg[row];
        int s1 = ldeg[row];                      // = s0 + deg (post-scatter)
        int rank = 0;
        for (int j = s0; j < s1; j++) {
            int vj = sh_col[j];
            rank += (vj < vi || (vj == vi && j < i)) ? 1 : 0;
        }
        col[gbase + s0 + rank] = vi & 0xffffff;
    }
    // fused Xs: rows b*128..+127, coalesced ushort4
    int rbase = b * 128;
    for (int i = t; i < 128 * 32; i += 256) {
        int rl = i >> 5;
        int gr = rbase + rl;
        if (gr >= N) break;
        float s = sdv[rl];
        float4 xv = ((const float4*)x)[(size_t)gr * 32 + (i & 31)];
        ushort4 o;
        o.x = f2bf(xv.x * s); o.y = f2bf(xv.y * s);
        o.z = f2bf(xv.z * s); o.w = f2bf(xv.w * s);
        ((ushort4*)Xs)[(size_t)gr * 32 + (i & 31)] = o;
    }
}

// Quarter-wave 8-deep batch: 8 independent ushort8 (16B/lane) row loads,
// tree-accumulate into acc[8]. 1 KB per wave-instr (4 rows).
#define QLOAD8(Pf, col, i)                                                       \
    {                                                                            \
        u16x8 v0 = *(const u16x8*)((Pf) + (size_t)(col)[(i) + 0] * 128);         \
        u16x8 v1 = *(const u16x8*)((Pf) + (size_t)(col)[(i) + 1] * 128);         \
        u16x8 v2 = *(const u16x8*)((Pf) + (size_t)(col)[(i) + 2] * 128);         \
        u16x8 v3 = *(const u16x8*)((Pf) + (size_t)(col)[(i) + 3] * 128);         \
        u16x8 v4 = *(const u16x8*)((Pf) + (size_t)(col)[(i) + 4] * 128);         \
        u16x8 v5 = *(const u16x8*)((Pf) + (size_t)(col)[(i) + 5] * 128);         \
        u16x8 v6 = *(const u16x8*)((Pf) + (size_t)(col)[(i) + 6] * 128);         \
        u16x8 v7 = *(const u16x8*)((Pf) + (size_t)(col)[(i) + 7] * 128);         \
        _Pragma("unroll") for (int j_ = 0; j_ < 8; j_++)                         \
            acc[j_] += ((bf2f(v0[j_]) + bf2f(v1[j_])) + (bf2f(v2[j_]) + bf2f(v3[j_]))) \
                     + ((bf2f(v4[j_]) + bf2f(v5[j_])) + (bf2f(v6[j_]) + bf2f(v7[j_]))); \
    }

// Masked quarter-wave tail: clamped idx + 0/1 selector, no serial chain.
#define QTAIL8(Pf, col, i, end)                                                  \
    if ((i) < (end)) {                                                           \
        int cl = (end) - 1;                                                      \
        int e1 = (i) + 1 < (end) ? (i) + 1 : cl, e2 = (i) + 2 < (end) ? (i) + 2 : cl; \
        int e3 = (i) + 3 < (end) ? (i) + 3 : cl, e4 = (i) + 4 < (end) ? (i) + 4 : cl; \
        int e5 = (i) + 5 < (end) ? (i) + 5 : cl, e6 = (i) + 6 < (end) ? (i) + 6 : cl; \
        int e7 = (i) + 7 < (end) ? (i) + 7 : cl;                                 \
        float m1 = (i) + 1 < (end) ? 1.f : 0.f, m2 = (i) + 2 < (end) ? 1.f : 0.f; \
        float m3 = (i) + 3 < (end) ? 1.f : 0.f, m4 = (i) + 4 < (end) ? 1.f : 0.f; \
        float m5 = (i) + 5 < (end) ? 1.f : 0.f, m6 = (i) + 6 < (end) ? 1.f : 0.f; \
        float m7 = (i) + 7 < (end) ? 1.f : 0.f;                                  \
        u16x8 v0 = *(const u16x8*)((Pf) + (size_t)(col)[(i)] * 128);             \
        u16x8 v1 = *(const u16x8*)((Pf) + (size_t)(col)[e1] * 128);              \
        u16x8 v2 = *(const u16x8*)((Pf) + (size_t)(col)[e2] * 128);              \
        u16x8 v3 = *(const u16x8*)((Pf) + (size_t)(col)[e3] * 128);              \
        u16x8 v4 = *(const u16x8*)((Pf) + (size_t)(col)[e4] * 128);              \
        u16x8 v5 = *(const u16x8*)((Pf) + (size_t)(col)[e5] * 128);              \
        u16x8 v6 = *(const u16x8*)((Pf) + (size_t)(col)[e6] * 128);              \
        u16x8 v7 = *(const u16x8*)((Pf) + (size_t)(col)[e7] * 128);              \
        _Pragma("unroll") for (int j_ = 0; j_ < 8; j_++)                         \
            acc[j_] += bf2f(v0[j_]) + m1 * bf2f(v1[j_]) + m2 * bf2f(v2[j_])      \
                     + m3 * bf2f(v3[j_]) + m4 * bf2f(v4[j_]) + m5 * bf2f(v5[j_]) \
                     + m6 * bf2f(v6[j_]) + m7 * bf2f(v7[j_]);                    \
    }

// ---------- gather2: quarter-wave per row, ushort8 loads, masked tail ----------
__global__ __launch_bounds__(256) void gather2_kernel(
    const int* __restrict__ rowbeg, const int* __restrict__ rowend,
    const int* __restrict__ col, const unsigned short* __restrict__ P,
    const float* __restrict__ dinv, const float* __restrict__ bias,
    float* __restrict__ OF, int N) {
    int gid = blockIdx.x * blockDim.x + threadIdx.x;
    int r = gid >> 4;
    if (r >= N) return;
    int l = gid & 15;
    const unsigned short* Pf = P + (size_t)l * 8;

    float acc[8];
    {
        u16x8 u = *(const u16x8*)(Pf + (size_t)r * 128);
#pragma unroll
        for (int j = 0; j < 8; j++) acc[j] = bf2f(u[j]);
    }
    int beg = rowbeg[r], end = rowend[r];
    int i = beg;
    for (; i + 7 < end; i += 8) QLOAD8(Pf, col, i)
    QTAIL8(Pf, col, i, end)
    float s = dinv[r];
    float4 b0 = *(const float4*)(bias + l * 8);
    float4 b1 = *(const float4*)(bias + l * 8 + 4);
    float4 o0, o1;
    o0.x = fmaxf(acc[0] * s + b0.x, 0.f);
    o0.y = fmaxf(acc[1] * s + b0.y, 0.f);
    o0.z = fmaxf(acc[2] * s + b0.z, 0.f);
    o0.w = fmaxf(acc[3] * s + b0.w, 0.f);
    o1.x = fmaxf(acc[4] * s + b1.x, 0.f);
    o1.y = fmaxf(acc[5] * s + b1.y, 0.f);
    o1.z = fmaxf(acc[6] * s + b1.z, 0.f);
    o1.w = fmaxf(acc[7] * s + b1.w, 0.f);
    *(float4*)(OF + (size_t)r * 128 + l * 8) = o0;
    *(float4*)(OF + (size_t)r * 128 + l * 8 + 4) = o1;
}

// ---------- fused gather1 + GEMM1 + GEMM2: 32-row tile, quarter-wave rows ----------
// Block 512 = 8 waves = 32 quarter-waves = 32 rows. Gather: quarter-wave qw
// owns row m0+qw, lane owns feats 8l..8l+7 (ushort8). GEMMs: two 16-row
// subtiles; waves 0-3 subtile 0 (GEMM1 4nt/wave, GEMM2 2nt/wave), waves 4-7
// subtile 1. LDS 25.6KB -> 4 blocks/CU = 32 waves resident.
__global__ __launch_bounds__(512, 4) void gemm_fused_kernel(
    const int* __restrict__ rowbeg, const int* __restrict__ rowend,
    const int* __restrict__ col, const unsigned short* __restrict__ Xs,
    const unsigned short* __restrict__ W1s, const unsigned short* __restrict__ W2s,
    const float* __restrict__ bias, const float* __restrict__ dinv,
    unsigned short* __restrict__ T, int M) {
    __shared__ unsigned short Xt[32 * XTSTRIDE];   // 8704 B: aggregated A tile
    __shared__ unsigned short Ht[32 * LDSTRIDE];   // 16896 B: H tile

    int t = threadIdx.x;
    int m0 = blockIdx.x * 32;
    int qw = t >> 4;            // quarter-wave 0..31 = local row
    int l  = t & 15;
    const unsigned short* Pf = Xs + (size_t)l * 8;

    {
        int r = m0 + qw;
        int rc = (r < M) ? r : (M - 1);
        float acc[8];
        {
            u16x8 u = *(const u16x8*)(Pf + (size_t)rc * 128);   // self-loop
#pragma unroll
            for (int j = 0; j < 8; j++) acc[j] = bf2f(u[j]);
        }
        int beg = rowbeg[rc], end = rowend[rc];
        int i = beg;
        for (; i + 7 < end; i += 8) QLOAD8(Pf, col, i)
        QTAIL8(Pf, col, i, end)
        float dvr = dinv[rc];
        u16x8 o;
#pragma unroll
        for (int j = 0; j < 8; j++) o[j] = f2bf(acc[j] * dvr);
        *(u16x8*)(Xt + qw * XTSTRIDE + l * 8) = o;
    }
    __syncthreads();

    int wave = t >> 6;          // 0..7
    int lane = t & 63;
    int mrow = lane & 15, quad = lane >> 4;
    int st = wave >> 2;         // subtile 0/1
    int wl = wave & 3;          // wave within subtile

    bf16x8 a[4];
#pragma unroll
    for (int kc = 0; kc < 4; kc++)
        a[kc] = *(const bf16x8*)(Xt + (st * 16 + mrow) * XTSTRIDE + kc * 32 + quad * 8);

    float dv[4];
#pragma unroll
    for (int i2 = 0; i2 < 4; i2++) {
        int gr = m0 + st * 16 + quad * 4 + i2;
        dv[i2] = dinv[gr < M ? gr : M - 1];
    }

    // ---- GEMM1: 16 nt per subtile, 4 per wave -> Ht ----
    const bf16x8* w1v = (const bf16x8*)W1s;
    for (int nt = wl * 4; nt < wl * 4 + 4; nt++) {
        f32x4 c = {0.f, 0.f, 0.f, 0.f};
#pragma unroll
        for (int kc = 0; kc < 4; kc++) {
            bf16x8 b = w1v[(nt * 4 + kc) * 64 + lane];
            c = __builtin_amdgcn_mfma_f32_16x16x32_bf16(a[kc], b, c, 0, 0, 0);
        }
        int colc = nt * 16 + mrow;
        float bb = bias[colc];
#pragma unroll
        for (int i2 = 0; i2 < 4; i2++) {
            float v = fmaxf(c[i2] + bb, 0.f) * dv[i2];
            Ht[(st * 16 + quad * 4 + i2) * LDSTRIDE + colc] = f2bf(v);
        }
    }
    __syncthreads();

    // ---- GEMM2: 8 nt per subtile, 2 per wave -> T ----
    bf16x8 hh[8];
    const unsigned short* hrow = Ht + (st * 16 + mrow) * LDSTRIDE + quad * 8;
#pragma unroll
    for (int kc = 0; kc < 8; kc++) hh[kc] = *(const bf16x8*)(hrow + kc * 32);
    const bf16x8* w2v = (const bf16x8*)W2s;
    for (int nt = wl * 2; nt < wl * 2 + 2; nt++) {
        f32x4 c = {0.f, 0.f, 0.f, 0.f};
#pragma unroll
        for (int kc = 0; kc < 8; kc++) {
            bf16x8 b = w2v[(nt * 8 + kc) * 64 + lane];
            c = __builtin_amdgcn_mfma_f32_16x16x32_bf16(hh[kc], b, c, 0, 0, 0);
        }
        int colc = nt * 16 + mrow;
#pragma unroll
        for (int i2 = 0; i2 < 4; i2++) {
            int gr = m0 + st * 16 + quad * 4 + i2;
            if (gr < M) T[(size_t)gr * 128 + colc] = f2bf(c[i2]);
        }
    }
}

extern "C" void kernel_launch(void* const* d_in, const int* in_sizes, int n_in,
                              void* d_out, int out_size, void* d_ws, size_t ws_size,
                              hipStream_t stream) {
    const float* x  = (const float*)d_in[0];
    const int* ei   = (const int*)d_in[1];     // int32 (JAX x64 disabled)
    const float* W1 = (const float*)d_in[2];
    const float* b1 = (const float*)d_in[3];
    const float* W2 = (const float*)d_in[4];
    const float* b2 = (const float*)d_in[5];
    float* out      = (float*)d_out;

    const int N = in_sizes[0] / 128;
    const int E = in_sizes[1] / 2;
    const int* src = ei;
    const int* dst = ei + E;

    const int nbuck = (N + BMASK) >> BSHIFT;                // 391
    int cap = E / nbuck + E / (4 * nbuck) + 512;            // ~3069
    if (cap > CAPMAX) cap = CAPMAX;                         // sh_col bound

    // Workspace: dinv | Ts | Xs | W1s | W2s | rowbeg | rowend | ctrl | bbuf | col
    float* ws = (float*)d_ws;
    size_t Np = ((size_t)N + 255) & ~(size_t)255;
    float*          dinv = ws;
    unsigned short* Ts   = (unsigned short*)(dinv + Np);    // N*128 bf16
    unsigned short* Xs   = Ts + (size_t)N * 128;            // N*128 bf16
    unsigned short* W1s  = Xs + (size_t)N * 128;            // 32768
    unsigned short* W2s  = W1s + 32768;                     // 32768
    int* rowbeg = (int*)(W2s + 32768);                      // N
    int* rowend = rowbeg + Np;                              // N
    int* ctrl   = rowend + Np;                              // bcur[512]
    int* bcur   = ctrl;
    unsigned int* bbuf = (unsigned int*)(ctrl + 512);       // nbuck*cap packed
    int* col    = (int*)(bbuf + (size_t)nbuck * cap);       // nbuck*cap

    // 1. weight swizzle + ctrl zero, then CSR build (+ deterministic rank sort)
    wswz_kernel<<<256, 256, 0, stream>>>(W1, W2, W1s, W2s, ctrl);
    int nbins = (E + 2047) / 2048;                          // 391
    bin_kernel<<<nbins, 256, 0, stream>>>(src, dst, bcur, bbuf, E, cap, nbuck);
    bucket_csr_kernel<<<nbuck, 256, 0, stream>>>(bcur, bbuf, x, col, rowbeg, rowend,
                                                 dinv, Xs, N, cap);

    // 2. fused gather1 + GEMM1 + GEMM2 -> Ts (32-row tiles, 8 waves)
    int mtiles = (N + 31) / 32;
    gemm_fused_kernel<<<mtiles, 512, 0, stream>>>(rowbeg, rowend, col, Xs,
                                                  W1s, W2s, b1, dinv, Ts, N);

    // 3. gather2 + fused bias/relu -> out (quarter-wave rows)
    int gth = N * 16;
    gather2_kernel<<<(gth + 255) / 256, 256, 0, stream>>>(rowbeg, rowend, col, Ts,
                                                          dinv, b2, out, N);
}

// Round 14
// 196.046 us; speedup vs baseline: 1.0235x; 1.0235x over previous
//
#include <hip/hip_runtime.h>

// GCN 2-layer, R27 = R25 verbatim (revert of R26's null quarter-wave/ushort8
// experiment). Evidence closed: gather is random-256B-row service-bound at
// ~4.2 TB/s effective - insensitive to depth (R24: 16-deep -21%), width
// (R26: 16B/lane null), and waves (R18/R25 plateau). Floor arithmetic:
// 2 gathers x 205MB / 4.2TB/s ~ 97us + prep ~40 + MLP/epilogue/launch ~55
// ~ 195-200us. Levers that would beat it: sub-bf16 payload (fails absmax
// budget) or graph locality (absent: uniform random edges).
//   wswz(+ctrl zero) | bin | bucket_csr(rank-sort,dinv,Xs) | gemm_fused | gather2
// Lessons: R7 R9 R11 R14 R16 R17 R18 R19 R21 R22 R23 R24 R26 (git log).

typedef short bf16x8 __attribute__((ext_vector_type(8)));
typedef float f32x4 __attribute__((ext_vector_type(4)));

#define LDSTRIDE 264   // H tile: 16 rows * 264 ushort = 528 B/row, 16B-aligned
#define XTSTRIDE 136   // A tile: 16 rows * 136 ushort = 272 B/row, 16B-aligned
#define BSHIFT 7       // 128 dsts per bucket
#define BMASK 127
#define CAPMAX 3072    // sh_col capacity (ints); host cap must be <= this

__device__ inline unsigned short f2bf(float f) {          // RNE
    unsigned int u = __float_as_uint(f);
    u += 0x7FFF + ((u >> 16) & 1);
    return (unsigned short)(u >> 16);
}
__device__ inline float bf2f(unsigned short h) {
    return __uint_as_float(((unsigned int)h) << 16);
}

// ---------- W swizzle into MFMA b-frag order + ctrl zero ----------
__device__ inline void swz1(const float* W, unsigned short* Ws, int K, int N, int i) {
    int k = i / N, n = i % N;
    int KC = K >> 5;
    size_t d = ((((size_t)(n >> 4) * KC + (k >> 5)) * 64) + ((k >> 3) & 3) * 16 + (n & 15)) * 8
               + (k & 7);
    Ws[d] = f2bf(W[i]);
}
__global__ void wswz_kernel(const float* __restrict__ W1, const float* __restrict__ W2,
                            unsigned short* __restrict__ W1s, unsigned short* __restrict__ W2s,
                            int* __restrict__ ctrl) {
    int i = blockIdx.x * blockDim.x + threadIdx.x;
    if (blockIdx.x == 0) {                     // zero ALL 512 ctrl ints
        for (int j = threadIdx.x; j < 512; j += 256) ctrl[j] = 0;
    }
    if (i < 32768) swz1(W1, W1s, 128, 256, i);
    else if (i < 65536) swz1(W2, W2s, 256, 128, i - 32768);
}

// ---------- pass 1: bin edges by dst>>7 (4 B packed) ----------
__global__ __launch_bounds__(256) void bin_kernel(
    const int* __restrict__ src, const int* __restrict__ dst,
    int* __restrict__ bcur, unsigned int* __restrict__ bbuf,
    int E, int cap, int nbuck) {
    __shared__ int cnt[512];
    __shared__ int base[512];
    int t = threadIdx.x;
    for (int i = t; i < nbuck; i += 256) cnt[i] = 0;
    __syncthreads();
    int e0 = blockIdx.x * 2048;
    unsigned int p_[8];
    int b_[8];
#pragma unroll
    for (int i = 0; i < 8; i++) {
        int e = e0 + i * 256 + t;
        if (e < E) {
            int s = src[e], d = dst[e];
            b_[i] = d >> BSHIFT;
            p_[i] = ((unsigned)(d & BMASK) << 24) | (unsigned)s;   // N < 2^24
            atomicAdd(&cnt[b_[i]], 1);
        } else b_[i] = -1;
    }
    __syncthreads();
    for (int b = t; b < nbuck; b += 256) {
        int c = cnt[b];
        base[b] = (c > 0) ? atomicAdd(&bcur[b], c) : 0;
    }
    __syncthreads();
    for (int i = t; i < nbuck; i += 256) cnt[i] = 0;   // reuse as cursor
    __syncthreads();
#pragma unroll
    for (int i = 0; i < 8; i++) {
        if (b_[i] >= 0) {
            int b = b_[i];
            int p = base[b] + atomicAdd(&cnt[b], 1);
            if (p >= 0 && p < cap) bbuf[(size_t)b * cap + p] = p_[i];
        }
    }
}

// ---------- pass 2: per-bucket (128 dsts) CSR + parallel rank sort + Xs ----------
__global__ __launch_bounds__(256) void bucket_csr_kernel(
    const int* __restrict__ bcur, const unsigned int* __restrict__ bbuf,
    const float* __restrict__ x,
    int* __restrict__ col, int* __restrict__ rowbeg, int* __restrict__ rowend,
    float* __restrict__ dinv, unsigned short* __restrict__ Xs, int N, int cap) {
    __shared__ int ldeg[128];
    __shared__ int sbeg[128];
    __shared__ int lrp[256];
    __shared__ float sdv[128];
    __shared__ int sh_col[CAPMAX];               // 12288 B: packed (row<<24)|src
    int b = blockIdx.x, t = threadIdx.x;
    int cnt = min(max(bcur[b], 0), cap);
    if (t < 128) ldeg[t] = 0;
    __syncthreads();
    const unsigned int* mybuf = bbuf + (size_t)b * cap;
    for (int i = t; i < cnt; i += 256)
        atomicAdd(&ldeg[mybuf[i] >> 24], 1);
    __syncthreads();
    int v = (t < 128) ? ldeg[t] : 0;
    lrp[t] = v;
    __syncthreads();
    for (int off = 1; off < 128; off <<= 1) {    // inclusive scan (128 live)
        int u = (t >= off) ? lrp[t - off] : 0;
        __syncthreads();
        lrp[t] += u;
        __syncthreads();
    }
    int excl = lrp[t] - v;
    int gbase = b * cap;
    if (t < 128) {
        int r = b * 128 + t;
        float dv = rsqrtf((float)v + 1.0f);      // self-loop adds 1
        sdv[t] = dv;
        if (r < N) {
            rowbeg[r] = gbase + excl;
            rowend[r] = gbase + excl + v;
            dinv[r] = dv;
        }
        sbeg[t] = excl;    // segment start (stable)
        ldeg[t] = excl;    // LOCAL scatter cursor
    }
    __syncthreads();
    for (int i = t; i < cnt; i += 256) {         // scatter packed vals into LDS
        unsigned int pr = mybuf[i];
        int p = atomicAdd(&ldeg[pr >> 24], 1);
        sh_col[p] = (int)pr;                     // keep row bits for compare
    }
    __syncthreads();
    // deterministic order via PARALLEL rank sort: slot = seg_start +
    // #{v_j < v_i} + #{v_j == v_i && j < i}; ties interchangeable -> array
    // content launch-invariant; independent LDS reads, no chains (R23).
    for (int i = t; i < cnt; i += 256) {
        int vi = sh_col[i];
        int row = ((unsigned)vi) >> 24;
        int s0 = sbeg[row];
        int s1 = ldeg[row];                      // = s0 + deg (post-scatter)
        int rank = 0;
        for (int j = s0; j < s1; j++) {
            int vj = sh_col[j];
            rank += (vj < vi || (vj == vi && j < i)) ? 1 : 0;
        }
        col[gbase + s0 + rank] = vi & 0xffffff;
    }
    // fused Xs: rows b*128..+127, coalesced ushort4
    int rbase = b * 128;
    for (int i = t; i < 128 * 32; i += 256) {
        int rl = i >> 5;
        int gr = rbase + rl;
        if (gr >= N) break;
        float s = sdv[rl];
        float4 xv = ((const float4*)x)[(size_t)gr * 32 + (i & 31)];
        ushort4 o;
        o.x = f2bf(xv.x * s); o.y = f2bf(xv.y * s);
        o.z = f2bf(xv.z * s); o.w = f2bf(xv.w * s);
        ((ushort4*)Xs)[(size_t)gr * 32 + (i & 31)] = o;
    }
}

// 8-deep batched row accumulate (measured sweet spot: 16-deep thrashed L1
// (R24); 16B/lane width null (R26)).
#define GLOAD8(Pf, col, i)                                                       \
    {                                                                            \
        ushort4 v0 = *(const ushort4*)((Pf) + (size_t)(col)[(i) + 0] * 128);     \
        ushort4 v1 = *(const ushort4*)((Pf) + (size_t)(col)[(i) + 1] * 128);     \
        ushort4 v2 = *(const ushort4*)((Pf) + (size_t)(col)[(i) + 2] * 128);     \
        ushort4 v3 = *(const ushort4*)((Pf) + (size_t)(col)[(i) + 3] * 128);     \
        ushort4 v4 = *(const ushort4*)((Pf) + (size_t)(col)[(i) + 4] * 128);     \
        ushort4 v5 = *(const ushort4*)((Pf) + (size_t)(col)[(i) + 5] * 128);     \
        ushort4 v6 = *(const ushort4*)((Pf) + (size_t)(col)[(i) + 6] * 128);     \
        ushort4 v7 = *(const ushort4*)((Pf) + (size_t)(col)[(i) + 7] * 128);     \
        ax += (bf2f(v0.x) + bf2f(v1.x)) + (bf2f(v2.x) + bf2f(v3.x))             \
            + (bf2f(v4.x) + bf2f(v5.x)) + (bf2f(v6.x) + bf2f(v7.x));            \
        ay += (bf2f(v0.y) + bf2f(v1.y)) + (bf2f(v2.y) + bf2f(v3.y))             \
            + (bf2f(v4.y) + bf2f(v5.y)) + (bf2f(v6.y) + bf2f(v7.y));            \
        az += (bf2f(v0.z) + bf2f(v1.z)) + (bf2f(v2.z) + bf2f(v3.z))             \
            + (bf2f(v4.z) + bf2f(v5.z)) + (bf2f(v6.z) + bf2f(v7.z));            \
        aw += (bf2f(v0.w) + bf2f(v1.w)) + (bf2f(v2.w) + bf2f(v3.w))             \
            + (bf2f(v4.w) + bf2f(v5.w)) + (bf2f(v6.w) + bf2f(v7.w));            \
    }

// Masked 8-batch tail: clamped idx + 0/1 selector, no serial dependent chain.
#define GTAIL8(Pf, col, i, end)                                                  \
    if ((i) < (end)) {                                                           \
        int cl = (end) - 1;                                                      \
        int e1 = (i) + 1 < (end) ? (i) + 1 : cl, e2 = (i) + 2 < (end) ? (i) + 2 : cl; \
        int e3 = (i) + 3 < (end) ? (i) + 3 : cl, e4 = (i) + 4 < (end) ? (i) + 4 : cl; \
        int e5 = (i) + 5 < (end) ? (i) + 5 : cl, e6 = (i) + 6 < (end) ? (i) + 6 : cl; \
        int e7 = (i) + 7 < (end) ? (i) + 7 : cl;                                 \
        float m1 = (i) + 1 < (end) ? 1.f : 0.f, m2 = (i) + 2 < (end) ? 1.f : 0.f; \
        float m3 = (i) + 3 < (end) ? 1.f : 0.f, m4 = (i) + 4 < (end) ? 1.f : 0.f; \
        float m5 = (i) + 5 < (end) ? 1.f : 0.f, m6 = (i) + 6 < (end) ? 1.f : 0.f; \
        float m7 = (i) + 7 < (end) ? 1.f : 0.f;                                  \
        ushort4 t0 = *(const ushort4*)((Pf) + (size_t)(col)[(i)] * 128);         \
        ushort4 t1 = *(const ushort4*)((Pf) + (size_t)(col)[e1] * 128);          \
        ushort4 t2 = *(const ushort4*)((Pf) + (size_t)(col)[e2] * 128);          \
        ushort4 t3 = *(const ushort4*)((Pf) + (size_t)(col)[e3] * 128);          \
        ushort4 t4 = *(const ushort4*)((Pf) + (size_t)(col)[e4] * 128);          \
        ushort4 t5 = *(const ushort4*)((Pf) + (size_t)(col)[e5] * 128);          \
        ushort4 t6 = *(const ushort4*)((Pf) + (size_t)(col)[e6] * 128);          \
        ushort4 t7 = *(const ushort4*)((Pf) + (size_t)(col)[e7] * 128);          \
        ax += bf2f(t0.x) + m1 * bf2f(t1.x) + m2 * bf2f(t2.x) + m3 * bf2f(t3.x)  \
            + m4 * bf2f(t4.x) + m5 * bf2f(t5.x) + m6 * bf2f(t6.x) + m7 * bf2f(t7.x); \
        ay += bf2f(t0.y) + m1 * bf2f(t1.y) + m2 * bf2f(t2.y) + m3 * bf2f(t3.y)  \
            + m4 * bf2f(t4.y) + m5 * bf2f(t5.y) + m6 * bf2f(t6.y) + m7 * bf2f(t7.y); \
        az += bf2f(t0.z) + m1 * bf2f(t1.z) + m2 * bf2f(t2.z) + m3 * bf2f(t3.z)  \
            + m4 * bf2f(t4.z) + m5 * bf2f(t5.z) + m6 * bf2f(t6.z) + m7 * bf2f(t7.z); \
        aw += bf2f(t0.w) + m1 * bf2f(t1.w) + m2 * bf2f(t2.w) + m3 * bf2f(t3.w)  \
            + m4 * bf2f(t4.w) + m5 * bf2f(t5.w) + m6 * bf2f(t6.w) + m7 * bf2f(t7.w); \
    }

// ---------- gather2: half-wave per row, 8-deep batches, masked tail ----------
__global__ __launch_bounds__(256) void gather2_kernel(
    const int* __restrict__ rowbeg, const int* __restrict__ rowend,
    const int* __restrict__ col, const unsigned short* __restrict__ P,
    const float* __restrict__ dinv, const float* __restrict__ bias,
    float* __restrict__ OF, int N) {
    int gid = blockIdx.x * blockDim.x + threadIdx.x;
    int r = gid >> 5;
    if (r >= N) return;
    int lane = gid & 31;
    const size_t off = (size_t)lane * 4;
    const unsigned short* Pf = P + off;

    ushort4 u = *(const ushort4*)(Pf + (size_t)r * 128);
    float ax = bf2f(u.x), ay = bf2f(u.y), az = bf2f(u.z), aw = bf2f(u.w);

    int beg = rowbeg[r], end = rowend[r];
    int i = beg;
    for (; i + 7 < end; i += 8) GLOAD8(Pf, col, i)
    GTAIL8(Pf, col, i, end)
    float s = dinv[r];
    float4 bb = *(const float4*)(bias + off);
    float4 o;
    o.x = fmaxf(ax * s + bb.x, 0.f);
    o.y = fmaxf(ay * s + bb.y, 0.f);
    o.z = fmaxf(az * s + bb.z, 0.f);
    o.w = fmaxf(aw * s + bb.w, 0.f);
    *(float4*)(OF + (size_t)r * 128 + off) = o;
}

// ---------- fused gather1 + GEMM1 + GEMM2, 1 half-wave per row, 8-deep ----------
__global__ __launch_bounds__(512, 4) void gemm_fused_kernel(
    const int* __restrict__ rowbeg, const int* __restrict__ rowend,
    const int* __restrict__ col, const unsigned short* __restrict__ Xs,
    const unsigned short* __restrict__ W1s, const unsigned short* __restrict__ W2s,
    const float* __restrict__ bias, const float* __restrict__ dinv,
    unsigned short* __restrict__ T, int M) {
    __shared__ unsigned short Xt[16 * XTSTRIDE];   // 4352 B: aggregated bf16 A tile
    __shared__ unsigned short Ht[16 * LDSTRIDE];   // 8448 B: H tile

    int t = threadIdx.x;
    int m0 = blockIdx.x * 16;
    int hw = t >> 5;            // half-wave 0..15 = local row
    int l  = t & 31;
    const unsigned short* Pf = Xs + (size_t)l * 4;

    {
        int r = m0 + hw;
        int rc = (r < M) ? r : (M - 1);
        ushort4 u = *(const ushort4*)(Pf + (size_t)rc * 128);   // self-loop
        float ax = bf2f(u.x), ay = bf2f(u.y), az = bf2f(u.z), aw = bf2f(u.w);
        int beg = rowbeg[rc], end = rowend[rc];
        int i = beg;
        for (; i + 7 < end; i += 8) GLOAD8(Pf, col, i)
        GTAIL8(Pf, col, i, end)
        float dvr = dinv[rc];
        ushort4 o;
        o.x = f2bf(ax * dvr); o.y = f2bf(ay * dvr);
        o.z = f2bf(az * dvr); o.w = f2bf(aw * dvr);
        *(ushort4*)(Xt + hw * XTSTRIDE + l * 4) = o;
    }
    __syncthreads();

    int wave = t >> 6;          // 0..7
    int lane = t & 63;
    int mrow = lane & 15, quad = lane >> 4;

    bf16x8 a[4];
#pragma unroll
    for (int kc = 0; kc < 4; kc++)
        a[kc] = *(const bf16x8*)(Xt + mrow * XTSTRIDE + kc * 32 + quad * 8);

    float dv[4];
#pragma unroll
    for (int i2 = 0; i2 < 4; i2++) {
        int gr = m0 + quad * 4 + i2;
        dv[i2] = dinv[gr < M ? gr : M - 1];
    }

    // ---- GEMM1: 16 nt tiles split 2 per wave -> Ht ----
    const bf16x8* w1v = (const bf16x8*)W1s;
    for (int nt = wave * 2; nt < wave * 2 + 2; nt++) {
        f32x4 c = {0.f, 0.f, 0.f, 0.f};
#pragma unroll
        for (int kc = 0; kc < 4; kc++) {
            bf16x8 b = w1v[(nt * 4 + kc) * 64 + lane];
            c = __builtin_amdgcn_mfma_f32_16x16x32_bf16(a[kc], b, c, 0, 0, 0);
        }
        int colc = nt * 16 + mrow;
        float bb = bias[colc];
#pragma unroll
        for (int i2 = 0; i2 < 4; i2++) {
            float v = fmaxf(c[i2] + bb, 0.f) * dv[i2];
            Ht[(quad * 4 + i2) * LDSTRIDE + colc] = f2bf(v);
        }
    }
    __syncthreads();

    // ---- GEMM2: 8 nt tiles, 1 per wave -> T ----
    bf16x8 hh[8];
    const unsigned short* hrow = Ht + mrow * LDSTRIDE + quad * 8;
#pragma unroll
    for (int kc = 0; kc < 8; kc++) hh[kc] = *(const bf16x8*)(hrow + kc * 32);
    const bf16x8* w2v = (const bf16x8*)W2s;
    {
        int nt = wave;
        f32x4 c = {0.f, 0.f, 0.f, 0.f};
#pragma unroll
        for (int kc = 0; kc < 8; kc++) {
            bf16x8 b = w2v[(nt * 8 + kc) * 64 + lane];
            c = __builtin_amdgcn_mfma_f32_16x16x32_bf16(hh[kc], b, c, 0, 0, 0);
        }
        int colc = nt * 16 + mrow;
#pragma unroll
        for (int i2 = 0; i2 < 4; i2++) {
            int gr = m0 + quad * 4 + i2;
            if (gr < M) T[(size_t)gr * 128 + colc] = f2bf(c[i2]);
        }
    }
}

extern "C" void kernel_launch(void* const* d_in, const int* in_sizes, int n_in,
                              void* d_out, int out_size, void* d_ws, size_t ws_size,
                              hipStream_t stream) {
    const float* x  = (const float*)d_in[0];
    const int* ei   = (const int*)d_in[1];     // int32 (JAX x64 disabled)
    const float* W1 = (const float*)d_in[2];
    const float* b1 = (const float*)d_in[3];
    const float* W2 = (const float*)d_in[4];
    const float* b2 = (const float*)d_in[5];
    float* out      = (float*)d_out;

    const int N = in_sizes[0] / 128;
    const int E = in_sizes[1] / 2;
    const int* src = ei;
    const int* dst = ei + E;

    const int nbuck = (N + BMASK) >> BSHIFT;                // 391
    int cap = E / nbuck + E / (4 * nbuck) + 512;            // ~3069
    if (cap > CAPMAX) cap = CAPMAX;                         // sh_col bound

    // Workspace: dinv | Ts | Xs | W1s | W2s | rowbeg | rowend | ctrl | bbuf | col
    float* ws = (float*)d_ws;
    size_t Np = ((size_t)N + 255) & ~(size_t)255;
    float*          dinv = ws;
    unsigned short* Ts   = (unsigned short*)(dinv + Np);    // N*128 bf16
    unsigned short* Xs   = Ts + (size_t)N * 128;            // N*128 bf16
    unsigned short* W1s  = Xs + (size_t)N * 128;            // 32768
    unsigned short* W2s  = W1s + 32768;                     // 32768
    int* rowbeg = (int*)(W2s + 32768);                      // N
    int* rowend = rowbeg + Np;                              // N
    int* ctrl   = rowend + Np;                              // bcur[512]
    int* bcur   = ctrl;
    unsigned int* bbuf = (unsigned int*)(ctrl + 512);       // nbuck*cap packed
    int* col    = (int*)(bbuf + (size_t)nbuck * cap);       // nbuck*cap

    // 1. weight swizzle + ctrl zero, then CSR build (+ deterministic rank sort)
    wswz_kernel<<<256, 256, 0, stream>>>(W1, W2, W1s, W2s, ctrl);
    int nbins = (E + 2047) / 2048;                          // 391
    bin_kernel<<<nbins, 256, 0, stream>>>(src, dst, bcur, bbuf, E, cap, nbuck);
    bucket_csr_kernel<<<nbuck, 256, 0, stream>>>(bcur, bbuf, x, col, rowbeg, rowend,
                                                 dinv, Xs, N, cap);

    // 2. fused gather1 + GEMM1 + GEMM2 -> Ts (8 waves per 16-row tile)
    int mtiles = (N + 15) / 16;
    gemm_fused_kernel<<<mtiles, 512, 0, stream>>>(rowbeg, rowend, col, Xs,
                                                  W1s, W2s, b1, dinv, Ts, N);

    // 3. gather2 + fused bias/relu -> out
    int gth = N * 32;
    gather2_kernel<<<(gth + 255) / 256, 256, 0, stream>>>(rowbeg, rowend, col, Ts,
                                                          dinv, b2, out, N);
}